// Round 6
// baseline (4022.338 us; speedup 1.0000x reference)
//
#include <hip/hip_runtime.h>
#include <hip/hip_bf16.h>

typedef __bf16 bf16;
typedef __bf16 bf16x8 __attribute__((ext_vector_type(8)));
typedef float f32x4 __attribute__((ext_vector_type(4)));

#define MODE_BIAS 1
#define MODE_RELU 2
#define MODE_BF16 4
#define MODE_F32  8
#define MODE_RES  16   // f32 residual
#define MODE_RESB 32   // bf16 residual
#define MODE_QKV  128

// ---------------------------------------------------------------------------
// Async 16B global->LDS stage
// ---------------------------------------------------------------------------
__device__ __forceinline__ void stage16(const bf16* g, bf16* l)
{
  __builtin_amdgcn_global_load_lds(
      (const __attribute__((address_space(1))) void*)g,
      (__attribute__((address_space(3))) void*)l, 16, 0, 0);
}

// ---------------------------------------------------------------------------
// gemm2: C[M,N] = A[M,K]*B^T (B is [N,K]).  M=gm*128, N=gn*128, K%64==0.
// 128x128 tile, BK=64 (two 32-slabs, 32 MFMA between barriers).
// 1-D grid with XCD-aware swizzle: launch 8*ceil(gm*gn/8) blocks;
// xcd = lin&7 owns a contiguous id-range (n-major, m-fastest) so each XCD's
// L2 holds a small slice of B and the whole A panel.
// ---------------------------------------------------------------------------
__global__ __launch_bounds__(256) void gemm2(
    const bf16* __restrict__ A, const bf16* __restrict__ B,
    float* __restrict__ Cf, bf16* __restrict__ Cb,
    const float* __restrict__ bias, const float* __restrict__ resf,
    const bf16* __restrict__ resb,
    int gm, int gn, int K, int lda, int ldb, int ldc, long qstride, int mode)
{
  int total = gm * gn;
  int per = (total + 7) >> 3;
  int id = (int)(blockIdx.x & 7) * per + (int)(blockIdx.x >> 3);
  if (id >= total) return;
  int bn0 = (id / gm) * 128;
  int bm0 = (id % gm) * 128;

  __shared__ __attribute__((aligned(16))) bf16 smem[16384];  // 32 KB
  bf16* sA = smem;            // [2][128][32]
  bf16* sB = smem + 8192;     // [2][128][32]

  int tid  = threadIdx.x;
  int lane = tid & 63;
  int wave = tid >> 6;
  int wm = (wave >> 1) * 64;
  int wn = (wave & 1) * 64;

  f32x4 acc[4][4];
  #pragma unroll
  for (int i = 0; i < 4; ++i)
    #pragma unroll
    for (int j = 0; j < 4; ++j)
      #pragma unroll
      for (int r = 0; r < 4; ++r) acc[i][j][r] = 0.f;

  int seg0 = wave, seg1 = wave + 4;
  int o0 = seg0 * 1024 + lane * 16;
  int r0s = o0 >> 6, c0b = o0 & 63;
  int o1 = seg1 * 1024 + lane * 16;
  int r1s = o1 >> 6, c1b = o1 & 63;

  const char* gA0 = (const char*)A + ((long)(bm0 + r0s) * lda) * 2 + c0b;
  const char* gA1 = (const char*)A + ((long)(bm0 + r1s) * lda) * 2 + c1b;
  const char* gB0 = (const char*)B + ((long)(bn0 + r0s) * ldb) * 2 + c0b;
  const char* gB1 = (const char*)B + ((long)(bn0 + r1s) * ldb) * 2 + c1b;

  for (int k0 = 0; k0 < K; k0 += 64) {
    const char* pA0 = gA0 + (long)k0 * 2;
    const char* pA1 = gA1 + (long)k0 * 2;
    const char* pB0 = gB0 + (long)k0 * 2;
    const char* pB1 = gB1 + (long)k0 * 2;
    stage16((const bf16*)pA0,        sA + seg0 * 512);
    stage16((const bf16*)pA1,        sA + seg1 * 512);
    stage16((const bf16*)(pA0 + 64), sA + 4096 + seg0 * 512);
    stage16((const bf16*)(pA1 + 64), sA + 4096 + seg1 * 512);
    stage16((const bf16*)pB0,        sB + seg0 * 512);
    stage16((const bf16*)pB1,        sB + seg1 * 512);
    stage16((const bf16*)(pB0 + 64), sB + 4096 + seg0 * 512);
    stage16((const bf16*)(pB1 + 64), sB + 4096 + seg1 * 512);
    __syncthreads();
    #pragma unroll
    for (int kh = 0; kh < 2; ++kh) {
      bf16x8 aF[4], bF[4];
      #pragma unroll
      for (int i = 0; i < 4; ++i)
        aF[i] = *(const bf16x8*)(&sA[kh * 4096 + (wm + i * 16 + (lane & 15)) * 32 + (lane >> 4) * 8]);
      #pragma unroll
      for (int j = 0; j < 4; ++j)
        bF[j] = *(const bf16x8*)(&sB[kh * 4096 + (wn + j * 16 + (lane & 15)) * 32 + (lane >> 4) * 8]);
      #pragma unroll
      for (int i = 0; i < 4; ++i)
        #pragma unroll
        for (int j = 0; j < 4; ++j)
          acc[i][j] = __builtin_amdgcn_mfma_f32_16x16x32_bf16(aF[i], bF[j], acc[i][j], 0, 0, 0);
    }
    __syncthreads();
  }

  int lg = lane >> 4;
  int r0 = lg * 4;
  int cc = lane & 15;

  if ((mode & MODE_QKV) && bn0 >= 8192) {
    // ---- V: transposed coalesced store via LDS (smem reused; K-loop done) ----
    bf16* sS = smem;   // [64][130]
    int nn0 = bn0 - 8192;
    #pragma unroll
    for (int ph = 0; ph < 2; ++ph) {
      if ((wn >> 6) == ph) {
        #pragma unroll
        for (int j = 0; j < 4; ++j) {
          int nl = j * 16 + cc;
          float bv = bias[bn0 + wn + j * 16 + cc];
          #pragma unroll
          for (int i = 0; i < 4; ++i)
            #pragma unroll
            for (int r = 0; r < 4; ++r) {
              int m = wm + i * 16 + r0 + r;
              sS[nl * 130 + m] = (bf16)(acc[i][j][r] + bv);
            }
        }
      }
      __syncthreads();
      #pragma unroll
      for (int u = 0; u < 16; ++u) {
        int nrow = u * 4 + wave;
        int d = nn0 + ph * 64 + nrow;
        int hh = d >> 9, dd = d & 511;
        unsigned int pv = *(const unsigned int*)&sS[nrow * 130 + lane * 2];
        int m0 = bm0 + 2 * lane;
        int bl = m0 / 168;
        int s  = m0 - bl * 168;     // even -> pair stays in row
        *(unsigned int*)&Cb[2 * qstride + ((long)(bl * 8 + hh) * 512 + dd) * 168 + s] = pv;
      }
      __syncthreads();
    }
    return;
  }

  #pragma unroll
  for (int j = 0; j < 4; ++j) {
    int gn_ = bn0 + wn + j * 16 + cc;
    float bv = (mode & MODE_BIAS) ? bias[gn_] : 0.f;
    #pragma unroll
    for (int i = 0; i < 4; ++i) {
      #pragma unroll
      for (int r = 0; r < 4; ++r) {
        int gm_ = bm0 + wm + i * 16 + r0 + r;
        float v = acc[i][j][r] + bv;
        if (mode & MODE_RES)  v += resf[(long)gm_ * ldc + gn_];
        if (mode & MODE_RESB) v += (float)resb[(long)gm_ * ldc + gn_];
        if (mode & MODE_RELU) v = fmaxf(v, 0.f);
        if (mode & MODE_QKV) {
          int part = gn_ >> 12;          // 0=Q 1=K (V handled above)
          int n = gn_ & 4095;
          Cb[(long)part * qstride + (long)gm_ * 4096 + n] = (bf16)v;
        } else if (mode & MODE_F32) {
          Cf[(long)gm_ * ldc + gn_] = v;
        } else {
          Cb[(long)gm_ * ldc + gn_] = (bf16)v;
        }
      }
    }
  }
}

// ---------------------------------------------------------------------------
// FUSED ATTENTION (O may alias Q; per-block reads own Q rows before writing)
// ---------------------------------------------------------------------------
__global__ __launch_bounds__(256) void attn_fused(
    const bf16* __restrict__ Q, const bf16* __restrict__ K,
    const bf16* __restrict__ Vt, bf16* __restrict__ O)
{
  __shared__ __attribute__((aligned(16))) bf16 sQ[64 * 32];
  __shared__ __attribute__((aligned(16))) bf16 sK[192 * 32];
  __shared__ __attribute__((aligned(16))) bf16 sP[64 * 200];
  __shared__ __attribute__((aligned(16))) bf16 sV[256 * 32];

  int mt = blockIdx.x;
  int bh = blockIdx.y;
  int bl = bh >> 3, h = bh & 7;
  int tid = threadIdx.x, lane = tid & 63, wave = tid >> 6;

  const bf16* Qb = Q + ((long)bl * 168 + mt * 64) * 4096 + h * 512;
  const bf16* Kb = K + (long)bl * 168 * 4096 + h * 512;
  const bf16* Vb = Vt + (long)bh * 512 * 168;

  #pragma unroll
  for (int idx = tid; idx < 64 * 16; idx += 256) {
    int rr = idx >> 4;
    sP[rr * 200 + 176 + (idx & 15)] = (bf16)0.f;
  }

  int o = wave * 1024 + lane * 16;
  int srw = o >> 6, scb = o & 63;

  const char* gQ = (const char*)Qb + (long)srw * 8192 + scb;
  const char* gK = (const char*)Kb + (long)srw * 8192 + scb;

  f32x4 sacc[11];
  #pragma unroll
  for (int j = 0; j < 11; ++j)
    #pragma unroll
    for (int r = 0; r < 4; ++r) sacc[j][r] = 0.f;

  for (int k0 = 0; k0 < 512; k0 += 32) {
    stage16((const bf16*)(gQ + (long)k0 * 2), &sQ[wave * 512]);
    stage16((const bf16*)(gK + (long)k0 * 2), &sK[wave * 512]);
    stage16((const bf16*)(gK + 64 * 8192 + (long)k0 * 2), &sK[(wave + 4) * 512]);
    stage16((const bf16*)(gK + 128 * 8192 + (long)k0 * 2), &sK[(wave + 8) * 512]);
    __syncthreads();
    bf16x8 aF = *(const bf16x8*)(&sQ[(wave * 16 + (lane & 15)) * 32 + (lane >> 4) * 8]);
    #pragma unroll
    for (int j = 0; j < 11; ++j) {
      bf16x8 bF = *(const bf16x8*)(&sK[(j * 16 + (lane & 15)) * 32 + (lane >> 4) * 8]);
      sacc[j] = __builtin_amdgcn_mfma_f32_16x16x32_bf16(aF, bF, sacc[j], 0, 0, 0);
    }
    __syncthreads();
  }

  int rbase = wave * 16 + ((lane >> 4) << 2);
  #pragma unroll
  for (int r = 0; r < 4; ++r) {
    int srow = mt * 64 + rbase + r;
    float mx = -1e30f;
    #pragma unroll
    for (int j = 0; j < 11; ++j) {
      int col = j * 16 + (lane & 15);
      float v = sacc[j][r] * 0.04419417382415922f;
      v = (col <= srow) ? v : -1e9f;
      sacc[j][r] = v;
      mx = fmaxf(mx, v);
    }
    #pragma unroll
    for (int off = 1; off < 16; off <<= 1) mx = fmaxf(mx, __shfl_xor(mx, off, 16));
    float sum = 0.f;
    #pragma unroll
    for (int j = 0; j < 11; ++j) {
      float e = __expf(sacc[j][r] - mx);
      sacc[j][r] = e;
      sum += e;
    }
    #pragma unroll
    for (int off = 1; off < 16; off <<= 1) sum += __shfl_xor(sum, off, 16);
    float inv = 1.f / sum;
    #pragma unroll
    for (int j = 0; j < 11; ++j)
      sP[(rbase + r) * 200 + j * 16 + (lane & 15)] = (bf16)(sacc[j][r] * inv);
  }

  const char* gV = (const char*)Vb + (long)srw * 336 + scb;
  #pragma unroll 1
  for (int nc = 0; nc < 2; ++nc) {
    f32x4 oacc[16];
    #pragma unroll
    for (int t = 0; t < 16; ++t)
      #pragma unroll
      for (int r = 0; r < 4; ++r) oacc[t][r] = 0.f;

    for (int k0 = 0; k0 < 192; k0 += 32) {
      #pragma unroll
      for (int u = 0; u < 4; ++u)
        stage16((const bf16*)(gV + (long)(nc * 256 + u * 64) * 336 + (long)k0 * 2),
                &sV[(wave + u * 4) * 512]);
      __syncthreads();
      bf16x8 aF = *(const bf16x8*)(&sP[(wave * 16 + (lane & 15)) * 200 + k0 + (lane >> 4) * 8]);
      #pragma unroll
      for (int t = 0; t < 16; ++t) {
        bf16x8 bF = *(const bf16x8*)(&sV[(t * 16 + (lane & 15)) * 32 + (lane >> 4) * 8]);
        oacc[t] = __builtin_amdgcn_mfma_f32_16x16x32_bf16(aF, bF, oacc[t], 0, 0, 0);
      }
      __syncthreads();
    }
    #pragma unroll
    for (int t = 0; t < 16; ++t) {
      int d = nc * 256 + t * 16 + (lane & 15);
      #pragma unroll
      for (int r = 0; r < 4; ++r) {
        int srow = mt * 64 + rbase + r;
        if (srow < 168)
          O[((long)bl * 168 + srow) * 4096 + h * 512 + d] = (bf16)oacc[t][r];
      }
    }
  }
}

// ---------------------------------------------------------------------------
// Weight transpose + f32->bf16
// ---------------------------------------------------------------------------
__global__ __launch_bounds__(256) void transpose_w(const float* __restrict__ in,
                                                   bf16* __restrict__ out,
                                                   int K, int N, long ostride, long obase)
{
  long zi = (long)blockIdx.z * K * N;
  long zo = (long)blockIdx.z * ostride + obase;
  __shared__ float t[32][33];
  int tx = threadIdx.x & 31;
  int ty = threadIdx.x >> 5;
  int n0 = blockIdx.x * 32;
  int k0 = blockIdx.y * 32;
  #pragma unroll
  for (int r = 0; r < 4; ++r) {
    int k = k0 + ty + r * 8, n = n0 + tx;
    if (k < K && n < N) t[ty + r * 8][tx] = in[zi + (long)k * N + n];
  }
  __syncthreads();
  #pragma unroll
  for (int r = 0; r < 4; ++r) {
    int n = n0 + ty + r * 8, k = k0 + tx;
    if (n < N && k < K) out[zo + (long)n * K + k] = (bf16)t[tx][ty + r * 8];
  }
}

__global__ __launch_bounds__(256) void merge_bias(const float* __restrict__ q,
                                                  const float* __restrict__ k,
                                                  const float* __restrict__ v,
                                                  float* __restrict__ o)
{
  int idx = blockIdx.x * 256 + threadIdx.x;
  if (idx >= 4 * 12288) return;
  int l = idx / 12288, r = idx - l * 12288;
  int part = r >> 12, n = r & 4095;
  const float* s = (part == 0) ? q : (part == 1) ? k : v;
  o[idx] = s[l * 4096 + n];
}

// ---------------------------------------------------------------------------
// Input projection: h = (x @ in_w + in_b) * sqrt(512) + pos_encoding
// ---------------------------------------------------------------------------
__global__ __launch_bounds__(256) void input_proj(const float* __restrict__ x,
                                                  const float* __restrict__ w,
                                                  const float* __restrict__ b,
                                                  float* __restrict__ hf,
                                                  bf16* __restrict__ hb)
{
  long idx = (long)blockIdx.x * 256 + threadIdx.x;
  long row = idx >> 9;
  int d = (int)(idx & 511);
  float acc = b[d];
  const float* xr = x + row * 10;
  #pragma unroll
  for (int f = 0; f < 10; ++f) acc += xr[f] * w[f * 512 + d];
  int s = (int)(row % 168);
  float rate = __expf(-(float)(d & ~1) * (9.210340371976184f / 512.f));
  float ang = (float)s * rate;
  float pe = (d & 1) ? cosf(ang) : sinf(ang);
  float v = acc * 22.627416997969522f + pe;
  hf[idx] = v;
  hb[idx] = (bf16)v;
}

// ---------------------------------------------------------------------------
// LayerNorm over 512; Yf write optional (nullptr -> skip)
// ---------------------------------------------------------------------------
__device__ __forceinline__ float block_sum256(float v, float* red)
{
  #pragma unroll
  for (int o = 32; o > 0; o >>= 1) v += __shfl_xor(v, o, 64);
  if ((threadIdx.x & 63) == 0) red[threadIdx.x >> 6] = v;
  __syncthreads();
  float tot = red[0] + red[1] + red[2] + red[3];
  __syncthreads();
  return tot;
}

__global__ __launch_bounds__(256) void ln_kernel(const float* __restrict__ X,
                                                 const float* __restrict__ g,
                                                 const float* __restrict__ bta,
                                                 float* __restrict__ Yf,
                                                 bf16* __restrict__ Yb)
{
  __shared__ float red[4];
  long row = blockIdx.x;
  int t = threadIdx.x;
  const float* x = X + row * 512;
  float v0 = x[t], v1 = x[t + 256];
  float mean = block_sum256(v0 + v1, red) * (1.f / 512.f);
  float d0 = v0 - mean, d1 = v1 - mean;
  float var = block_sum256(d0 * d0 + d1 * d1, red) * (1.f / 512.f);
  float rs = rsqrtf(var + 1e-9f);
  float y0 = d0 * rs * g[t] + bta[t];
  float y1 = d1 * rs * g[t + 256] + bta[t + 256];
  if (Yf) {
    Yf[row * 512 + t] = y0;
    Yf[row * 512 + t + 256] = y1;
  }
  Yb[row * 512 + t] = (bf16)y0;
  Yb[row * 512 + t + 256] = (bf16)y1;
}

// ---------------------------------------------------------------------------
// Output projection
// ---------------------------------------------------------------------------
__global__ __launch_bounds__(256) void out_proj(const float* __restrict__ hf,
                                                const float* __restrict__ ow,
                                                const float* __restrict__ ob,
                                                float* __restrict__ out)
{
  int gid = blockIdx.x * 256 + threadIdx.x;
  int wid = gid >> 6;
  int lane = gid & 63;
  if (wid >= 64 * 48) return;
  int b = wid / 48, j = wid - b * 48;
  long row = (long)b * 168 + 120 + j;
  const float* x = hf + row * 512;
  float s = 0.f;
  #pragma unroll
  for (int t = 0; t < 8; ++t) s += x[lane + t * 64] * ow[lane + t * 64];
  #pragma unroll
  for (int o = 32; o > 0; o >>= 1) s += __shfl_xor(s, o, 64);
  if (lane == 0) out[wid] = s + ob[0];
}

// ---------------------------------------------------------------------------
extern "C" void kernel_launch(void* const* d_in, const int* in_sizes, int n_in,
                              void* d_out, int out_size, void* d_ws, size_t ws_size,
                              hipStream_t stream)
{
  const float* x     = (const float*)d_in[0];
  const float* in_w  = (const float*)d_in[2];
  const float* in_b  = (const float*)d_in[3];
  const float* wq_w  = (const float*)d_in[4];
  const float* wq_b  = (const float*)d_in[5];
  const float* wk_w  = (const float*)d_in[6];
  const float* wk_b  = (const float*)d_in[7];
  const float* wv_w  = (const float*)d_in[8];
  const float* wv_b  = (const float*)d_in[9];
  const float* dn_w  = (const float*)d_in[10];
  const float* dn_b  = (const float*)d_in[11];
  const float* mh_w  = (const float*)d_in[12];
  const float* mh_b  = (const float*)d_in[13];
  const float* mo_w  = (const float*)d_in[14];
  const float* mo_b  = (const float*)d_in[15];
  const float* ln1_g = (const float*)d_in[16];
  const float* ln1_b = (const float*)d_in[17];
  const float* ln3_g = (const float*)d_in[18];
  const float* ln3_b = (const float*)d_in[19];
  const float* out_w = (const float*)d_in[20];
  const float* out_b = (const float*)d_in[21];
  float* out = (float*)d_out;

  auto al = [](size_t b) { return (b + 255) & ~(size_t)255; };
  size_t off = 0;
  auto alloc = [&](size_t bytes) -> char* {
    char* p = (char*)d_ws + off;
    off += al(bytes);
    return p;
  };

  // --- persistent buffers ---
  bf16*  wqkvT = (bf16*)alloc(4L * 12288 * 512 * 2);  // [L][12288][512]
  float* qkvB  = (float*)alloc(4L * 12288 * 4);
  bf16*  dnT   = (bf16*)alloc(4L * 512 * 4096 * 2);
  bf16*  mhT   = (bf16*)alloc(4L * 2048 * 512 * 2);
  bf16*  moT   = (bf16*)alloc(4L * 512 * 2048 * 2);
  float* hF    = (float*)alloc(10752L * 512 * 4);     // residual stream f32
  bf16*  hB    = (bf16*)alloc(10752L * 512 * 2);      // residual stream bf16
  float* Xf    = (float*)alloc(10752L * 512 * 4);     // pre-LN full-M scratch
  size_t fixed = off;

  // chunk size: CB=32 if the 3x Q/K/Vt region fits, else CB=16 (known to fit).
  int CB = 16;
  {
    long qs32 = 32L * 168 * 4096;
    if (fixed + al((size_t)(3 * qs32) * 2) <= ws_size) CB = 32;
  }
  const int  NC = 64 / CB;
  const long Mc = (long)CB * 168;
  const long qstride = Mc * 4096;
  bf16* Qc = (bf16*)alloc((size_t)(3 * qstride) * 2);
  bf16* Kc  = Qc + qstride;
  bf16* Vtc = Qc + 2 * qstride;
  bf16* h1b = Qc;                                     // [10752,512]  (alias)
  bf16* m1c = Qc + 10752L * 512;                      // [10752,2048] (alias)

  // --- weight prep ---
  transpose_w<<<dim3(128, 16, 4), 256, 0, stream>>>(wq_w, wqkvT, 512, 4096, 12288L * 512, 0);
  transpose_w<<<dim3(128, 16, 4), 256, 0, stream>>>(wk_w, wqkvT, 512, 4096, 12288L * 512, 4096L * 512);
  transpose_w<<<dim3(128, 16, 4), 256, 0, stream>>>(wv_w, wqkvT, 512, 4096, 12288L * 512, 8192L * 512);
  transpose_w<<<dim3(16, 128, 4), 256, 0, stream>>>(dn_w, dnT, 4096, 512, 512L * 4096, 0);
  transpose_w<<<dim3(64, 16, 4), 256, 0, stream>>>(mh_w, mhT, 512, 2048, 2048L * 512, 0);
  transpose_w<<<dim3(16, 64, 4), 256, 0, stream>>>(mo_w, moT, 2048, 512, 512L * 2048, 0);
  merge_bias<<<(4 * 12288 + 255) / 256, 256, 0, stream>>>(wq_b, wk_b, wv_b, qkvB);

  input_proj<<<10752 * 512 / 256, 256, 0, stream>>>(x, in_w, in_b, hF, hB);

  const int cM = (int)(Mc / 128);                 // 21 or 42
  auto blocks = [](int gm, int gn) { return ((gm * gn + 7) / 8) * 8; };

  for (int l = 0; l < 4; ++l) {
    // ---- chunked: QKV -> attention (O in-place over Qc) -> dn+res -> Xf ----
    for (int c = 0; c < NC; ++c) {
      long row0 = (long)c * Mc;

      gemm2<<<blocks(cM, 96), 256, 0, stream>>>(
          hB + row0 * 512, wqkvT + (long)l * 12288 * 512, nullptr, Qc,
          qkvB + (long)l * 12288, nullptr, nullptr,
          cM, 96, 512, 512, 512, 0, qstride, MODE_BIAS | MODE_QKV);

      attn_fused<<<dim3(3, CB * 8), 256, 0, stream>>>(Qc, Kc, Vtc, Qc);

      gemm2<<<blocks(cM, 4), 256, 0, stream>>>(
          Qc, dnT + (long)l * 512 * 4096, Xf + row0 * 512, nullptr,
          dn_b + (long)l * 512, hF + row0 * 512, nullptr,
          cM, 4, 4096, 4096, 4096, 512, 0, MODE_BIAS | MODE_RES | MODE_F32);
    }

    // ---- full-M: ln1 -> h1b (bf16 only; overwrites dead chunk region) ----
    ln_kernel<<<10752, 256, 0, stream>>>(Xf, ln1_g + l * 512, ln1_b + l * 512,
                                         nullptr, h1b);

    // ---- full-M MLP ----
    gemm2<<<blocks(84, 16), 256, 0, stream>>>(
        h1b, mhT + (long)l * 2048 * 512, nullptr, m1c,
        mh_b + (long)l * 2048, nullptr, nullptr,
        84, 16, 512, 512, 512, 2048, 0, MODE_BIAS | MODE_RELU | MODE_BF16);

    gemm2<<<blocks(84, 4), 256, 0, stream>>>(
        m1c, moT + (long)l * 512 * 2048, Xf, nullptr,
        mo_b + (long)l * 512, nullptr, h1b,
        84, 4, 2048, 2048, 2048, 512, 0, MODE_BIAS | MODE_RESB | MODE_F32);

    ln_kernel<<<10752, 256, 0, stream>>>(Xf, ln3_g + l * 512, ln3_b + l * 512,
                                         hF, hB);
  }

  out_proj<<<(64 * 48 * 64) / 256, 256, 0, stream>>>(hF, out_w, out_b, out);
}